// Round 1
// baseline (159.759 us; speedup 1.0000x reference)
//
#include <hip/hip_runtime.h>
#include <math.h>

#define C 8192
#define D 1024
#define BATCH 1024
#define PM 0.95f
#define PMC 0.05f
// values pre-scaled by 8 before fp8 quant; dot comes out 64x too big.
// epilogue uses 10/64 = 0.15625 (exact in fp32).
#define INVT_SCALED 0.15625f

typedef unsigned char u8;
typedef __attribute__((ext_vector_type(16))) float f32x16;

#define GLOBAL_AS(p) ((const __attribute__((address_space(1))) void*)(p))
#define LDS_AS(p) ((__attribute__((address_space(3))) void*)(p))

// ---------------------------------------------------------------------------
// EMA + fp8 quantize, one wave per class (4 classes/block, 2048 blocks).
// Verified rounds 7-13. fp8 layout (512-B k-units for 32x32x16 fp8 MFMA):
//   element (row c, k) -> P8[(c>>5)*32768 + (k>>4)*512 + ((k>>3)&1)*256 + (c&31)*8 + (k&7)]
__global__ __launch_bounds__(256) void ema_split_kernel(const float* __restrict__ feat,
                                                        const int* __restrict__ labels,
                                                        const float* __restrict__ protos,
                                                        u8* __restrict__ P8,
                                                        float* __restrict__ rowsum,
                                                        float* __restrict__ out) {
    __shared__ int sl[BATCH];
    const int t = threadIdx.x, w = t >> 6, lane = t & 63;
    const int c = blockIdx.x * 4 + w;

    if (blockIdx.x < 32) rowsum[blockIdx.x * 256 + t] = 0.0f;
    if (blockIdx.x == 0 && t == 0) out[0] = 0.0f;

    for (int i = t; i < BATCH; i += 256) sl[i] = labels[i];
    __syncthreads();

    float4 v[4];
    #pragma unroll
    for (int s = 0; s < 4; ++s)
        v[s] = *(const float4*)(protos + (size_t)c * D + s * 256 + lane * 4);

    for (int base = 0; base < BATCH; base += 64) {
        unsigned long long mask = __ballot(sl[base + lane] == c);
        while (mask) {
            const int b = __ffsll((long long)mask) - 1;
            mask &= mask - 1;
            const int idx = base + b;
            float ss = 0.0f;
            #pragma unroll
            for (int s = 0; s < 4; ++s) {
                const float4 f = *(const float4*)(feat + (size_t)idx * D + s * 256 + lane * 4);
                v[s].x = v[s].x * PM + f.x * PMC;
                v[s].y = v[s].y * PM + f.y * PMC;
                v[s].z = v[s].z * PM + f.z * PMC;
                v[s].w = v[s].w * PM + f.w * PMC;
                ss += v[s].x * v[s].x + v[s].y * v[s].y + v[s].z * v[s].z + v[s].w * v[s].w;
            }
            #pragma unroll
            for (int off = 32; off > 0; off >>= 1) ss += __shfl_xor(ss, off);
            const float inv = 1.0f / fmaxf(sqrtf(ss), 1e-12f);
            #pragma unroll
            for (int s = 0; s < 4; ++s) {
                v[s].x *= inv; v[s].y *= inv; v[s].z *= inv; v[s].w *= inv;
            }
        }
    }

    u8* ob = P8 + (size_t)(c >> 5) * 32768 + (c & 31) * 8;
    #pragma unroll
    for (int s = 0; s < 4; ++s) {
        const int k0 = s * 256 + lane * 4;
        const size_t off = (size_t)(k0 >> 4) * 512 + ((k0 >> 3) & 1) * 256 + (k0 & 7);
        int p = __builtin_amdgcn_cvt_pk_fp8_f32(v[s].x * 8.0f, v[s].y * 8.0f, 0, false);
        p = __builtin_amdgcn_cvt_pk_fp8_f32(v[s].z * 8.0f, v[s].w * 8.0f, p, true);
        *(unsigned int*)(ob + off) = (unsigned int)p;
    }
}

// ---------------------------------------------------------------------------
// fp8 Gram, mfma_f32_32x32x16_fp8_fp8. r13 deep pipeline (5 LDS buffers,
// 40 KB, oldest-2 vmcnt waits, 4 blocks/CU) + register-level fragment
// prefetch (two frag sets; LDS latency hidden behind MFMA issue).
//
// r14 PACKING FIX: grid was 2080 equal blocks at 4 blocks/CU = 1024 slots ->
// 3 dispatch rounds, last round 32/1024 full (~25 us of a mostly-idle
// machine; MfmaUtil 37% vs ~62% in-round). Now: 1024 persistent blocks
// (exactly one per slot, all resident at t=0), static tile lists over the
// lexicographic triangle enumeration l in [0,2080):
//   block b -> tiles {2b, 2b+1};  leftover tiles 2048+e -> block 33e
// (stride 33 spreads the 32 heavy blocks across XCDs AND CUs: e%8 covers
// all XCDs, 33e/8 distinct CU offsets). Per-CU work: 8 tiles (9 on heavy
// CUs) vs effective 12 before -> predicted ~56 us. Same-bi tile pairs keep
// the A panel L2-hot for the second tile.
// Per-tile body is the verified r13 pipeline verbatim; __syncthreads() at
// tile top (a) protects the epilogue's lds[0] scratch from the next tile's
// global_load_lds and (b) re-establishes vmcnt=0 for the counted waits.
// Triangle cover bi<=bj; diag blocks mask li>=lj -> rowsum == sum_neg.
__global__ __launch_bounds__(256, 4) void gram8_kernel(const u8* __restrict__ P8,
                                                       float* __restrict__ rowsum) {
    __shared__ u8 lds[5][8192];      // per buf: A tiles 0..3 @ a*1024, B @ 4096+
    const int t = threadIdx.x, w = t >> 6, lane = t & 63;
    const int bb = blockIdx.x;

    const int qi = w >> 1, qj = w & 1;
    const int aoff = qi * 2048 + lane * 8;          // A tile base within buf
    const int boff = 4096 + qj * 2048 + lane * 8;   // B tile base within buf
    const int ldsA = w * 1024, ldsB = 4096 + w * 1024;

    const int nt = (bb % 33 == 0) ? 3 : 2;          // 33e <= 1023 for e<32

    f32x16 acc[2][2];
    long fa[2][2], fb[2][2];   // [reg set][tile]

#define STAGE(KC, BUF)                                                         \
    __builtin_amdgcn_global_load_lds(GLOBAL_AS(gsrcA + (size_t)(KC) * 1024),   \
                                     LDS_AS(&lds[BUF][ldsA]), 16, 0, 0);       \
    __builtin_amdgcn_global_load_lds(GLOBAL_AS(gsrcB + (size_t)(KC) * 1024),   \
                                     LDS_AS(&lds[BUF][ldsB]), 16, 0, 0);

#define PF(SET, BUF, KK)                                                       \
    fa[SET][0] = *(const long*)&lds[BUF][aoff + (KK) * 512];                   \
    fa[SET][1] = *(const long*)&lds[BUF][aoff + 1024 + (KK) * 512];            \
    fb[SET][0] = *(const long*)&lds[BUF][boff + (KK) * 512];                   \
    fb[SET][1] = *(const long*)&lds[BUF][boff + 1024 + (KK) * 512];

#define MFMA4(SET)                                                             \
    acc[0][0] = __builtin_amdgcn_mfma_f32_32x32x16_fp8_fp8(fa[SET][0], fb[SET][0], acc[0][0], 0, 0, 0); \
    acc[0][1] = __builtin_amdgcn_mfma_f32_32x32x16_fp8_fp8(fa[SET][0], fb[SET][1], acc[0][1], 0, 0, 0); \
    acc[1][0] = __builtin_amdgcn_mfma_f32_32x32x16_fp8_fp8(fa[SET][1], fb[SET][0], acc[1][0], 0, 0, 0); \
    acc[1][1] = __builtin_amdgcn_mfma_f32_32x32x16_fp8_fp8(fa[SET][1], fb[SET][1], acc[1][1], 0, 0, 0);

#define WAITV(N) asm volatile("s_waitcnt vmcnt(" #N ")" ::: "memory")

    for (int tt = 0; tt < nt; ++tt) {
        // tile index in lex triangle enumeration
        const int l = (tt == 2) ? 2048 + bb / 33 : 2 * bb + tt;
        int rem = l, bi = 0;
        while (rem >= 64 - bi) { rem -= 64 - bi; ++bi; }   // uniform SALU, <=64 iters
        const int bj = bi + rem;
        const bool diag = (bi == bj);

        // per-wave staging: 2 glds x 1 KB per chunk (A tile w, B tile w)
        const u8* gsrcA = P8 + (size_t)(bi * 4 + w) * 32768 + lane * 16;
        const u8* gsrcB = P8 + (size_t)(bj * 4 + w) * 32768 + lane * 16;

        #pragma unroll
        for (int a = 0; a < 2; ++a)
            #pragma unroll
            for (int b = 0; b < 2; ++b)
                #pragma unroll
                for (int e = 0; e < 16; ++e) acc[a][b][e] = 0.0f;

        // WAR vs previous tile's epilogue lds reads; also drains vmcnt to 0
        // so the per-tile counted-wait discipline starts clean.
        __syncthreads();

        // prologue: stage chunks 0..3 into bufs 0..3 (8 glds outstanding/wave)
        STAGE(0, 0); STAGE(1, 1); STAGE(2, 2); STAGE(3, 3);
        WAITV(4);                                // chunks 0,1 resident
        __builtin_amdgcn_s_barrier();
        PF(0, 0, 0);                             // step 0 (chunk 0, kk=0)

        int cb = 0;                              // buffer of chunk kc (kc % 5)
        for (int kc = 0; kc < 28; ++kc) {
            const int sb = (cb >= 1) ? cb - 1 : 4;       // (kc+4) % 5
            STAGE(kc + 4, sb);
            const int nb = (cb == 4) ? 0 : cb + 1;       // buffer of chunk kc+1
            PF(1, cb, 1);                        // step 2kc+1 (same chunk)
            MFMA4(0);                            // step 2kc
            PF(0, nb, 0);                        // step 2kc+2 (chunk kc+1 - certified)
            MFMA4(1);                            // step 2kc+1
            WAITV(4);                            // certifies chunks kc+1, kc+2
            __builtin_amdgcn_s_barrier();
            cb = nb;
        }
        // peeled tail (cb == 3): chunks 28..31 in bufs 3,4,0,1
        PF(1, 3, 1); MFMA4(0);                   // steps 56/57
        PF(0, 4, 0); MFMA4(1);
        WAITV(2); __builtin_amdgcn_s_barrier();  // certifies chunk 30
        PF(1, 4, 1); MFMA4(0);                   // steps 58/59
        PF(0, 0, 0); MFMA4(1);
        WAITV(0); __builtin_amdgcn_s_barrier();  // certifies chunk 31
        PF(1, 0, 1); MFMA4(0);                   // steps 60/61
        PF(0, 1, 0); MFMA4(1);
        PF(1, 1, 1); MFMA4(0);                   // steps 62/63
        MFMA4(1);

        // epilogue: exp(acc*10/64), diag-block triangle mask, row/col partials.
        // C layout (32x32): col = lane&31, row = (reg&3) + 8*(reg>>2) + 4*(lane>>5)
        __syncthreads();                         // K-loop fully done; lds reusable
        float* rpart = (float*)&lds[0][0];
        float* cpart = (float*)&lds[0][512];
        if (t < 128) { rpart[t] = 0.0f; cpart[t] = 0.0f; }
        __syncthreads();
        const int half = lane >> 5, col = lane & 31;
        float csum[2] = {0.0f, 0.0f};
        #pragma unroll
        for (int ti = 0; ti < 2; ++ti) {
            float rs[16];
            #pragma unroll
            for (int reg = 0; reg < 16; ++reg) rs[reg] = 0.0f;
            #pragma unroll
            for (int tj = 0; tj < 2; ++tj) {
                const int lj = qj * 64 + tj * 32 + col;
                #pragma unroll
                for (int reg = 0; reg < 16; ++reg) {
                    const int li = qi * 64 + ti * 32 + (reg & 3) + 8 * (reg >> 2) + 4 * half;
                    float e = __expf(acc[ti][tj][reg] * INVT_SCALED);
                    if (diag && li >= lj) e = 0.0f;      // bi<bj blocks: always li<lj globally
                    rs[reg] += e;
                    csum[tj] += e;
                }
            }
            #pragma unroll
            for (int reg = 0; reg < 16; ++reg) {
                float v = rs[reg];
                v += __shfl_xor(v, 1); v += __shfl_xor(v, 2); v += __shfl_xor(v, 4);
                v += __shfl_xor(v, 8); v += __shfl_xor(v, 16);
                if (col == 0)
                    atomicAdd(&rpart[qi * 64 + ti * 32 + (reg & 3) + 8 * (reg >> 2) + 4 * half], v);
            }
        }
        #pragma unroll
        for (int tj = 0; tj < 2; ++tj) {
            float v = csum[tj];
            v += __shfl_xor(v, 32);
            if (half == 0) atomicAdd(&cpart[qj * 64 + tj * 32 + col], v);
        }
        __syncthreads();
        if (t < 128) atomicAdd(&rowsum[bi * 128 + t], rpart[t]);
        else         atomicAdd(&rowsum[bj * 128 + (t - 128)], cpart[t - 128]);
    }
}

// ---------------------------------------------------------------------------
// rowsum == sum_neg (diag + lower triangle excluded in gram)
__global__ __launch_bounds__(256) void final2_kernel(const float* __restrict__ rowsum,
                                                     float* __restrict__ out) {
    __shared__ float red[4];
    const int t = threadIdx.x;
    const int i = blockIdx.x * 256 + t;
    float v = logf(rowsum[i] * (1.0f / (float)(C - 1)));
    #pragma unroll
    for (int off = 32; off > 0; off >>= 1) v += __shfl_down(v, off);
    if ((t & 63) == 0) red[t >> 6] = v;
    __syncthreads();
    if (t == 0)
        atomicAdd(out, (red[0] + red[1] + red[2] + red[3]) * (1.0f / (float)C));
}

// ---------------------------------------------------------------------------
extern "C" void kernel_launch(void* const* d_in, const int* in_sizes, int n_in,
                              void* d_out, int out_size, void* d_ws, size_t ws_size,
                              hipStream_t stream) {
    const float* feat = (const float*)d_in[0];
    const int* labels = (const int*)d_in[1];
    const float* protos = (const float*)d_in[2];
    float* out = (float*)d_out;
    float* rowsum = (float*)d_ws;               // 32 KB
    u8* P8 = (u8*)((char*)d_ws + 32768);        // 8 MiB packed fp8 protos

    ema_split_kernel<<<C / 4, 256, 0, stream>>>(feat, labels, protos, P8, rowsum, out);
    gram8_kernel<<<1024, 256, 0, stream>>>(P8, rowsum);
    final2_kernel<<<C / 256, 256, 0, stream>>>(rowsum, out);
}